// Round 13
// baseline (200.093 us; speedup 1.0000x reference)
//
#include <hip/hip_runtime.h>
#include <stdint.h>

typedef __attribute__((ext_vector_type(8))) short short8;
typedef __attribute__((ext_vector_type(4))) float floatx4;
typedef __attribute__((ext_vector_type(16))) float floatx16;

__device__ inline unsigned short f2bf(float x) {
  union { float f; unsigned int u; } v; v.f = x;
  unsigned int r = v.u + 0x7FFFu + ((v.u >> 16) & 1u);  // RNE
  return (unsigned short)(r >> 16);
}

// ---------------------------------------------------------------------------
// pack_all: one dispatch does both packs. (verified, unchanged)
//   blocks [0,4096):    A_bf16[4096][2048] = bf16([x | h])
//   blocks [4096,6144): Wt_perm[4096][2048] = bf16(W^T) gate-interleaved:
//                       R = (h>>5)*128 + ((h>>4)&1)*64 + g*16 + (h&15)
// ---------------------------------------------------------------------------
__global__ void pack_all(const float* __restrict__ x, const float* __restrict__ h,
                         const float* __restrict__ wi, const float* __restrict__ wh,
                         unsigned short* __restrict__ A,
                         unsigned short* __restrict__ Wt) {
  int bid = blockIdx.x;
  int t = threadIdx.x;
  if (bid < 4096) {
    int idx = bid * 256 + t;
    int row = idx >> 8;
    int kc  = (idx & 255) << 3;
    const float* src = (kc < 1024) ? (x + (size_t)row * 1024 + kc)
                                   : (h + (size_t)row * 1024 + (kc - 1024));
    float4 a = ((const float4*)src)[0];
    float4 b = ((const float4*)src)[1];
    uint4 o;
    o.x = f2bf(a.x) | ((unsigned)f2bf(a.y) << 16);
    o.y = f2bf(a.z) | ((unsigned)f2bf(a.w) << 16);
    o.z = f2bf(b.x) | ((unsigned)f2bf(b.y) << 16);
    o.w = f2bf(b.z) | ((unsigned)f2bf(b.w) << 16);
    *(uint4*)(A + (size_t)row * 2048 + kc) = o;
  } else {
    __shared__ float tile[64][65];
    int b2 = bid - 4096;
    int kt = b2 & 31;
    int nt = b2 >> 5;
    int k0 = kt << 6, n0 = nt << 6;
    const float* src = (k0 < 1024) ? (wi + (size_t)k0 * 4096)
                                   : (wh + (size_t)(k0 - 1024) * 4096);
    int c4 = (t & 15) << 2, rr = t >> 4;
#pragma unroll
    for (int p = 0; p < 4; ++p) {
      int kk = rr + p * 16;
      float4 v = *(const float4*)(src + (size_t)kk * 4096 + n0 + c4);
      tile[kk][c4 + 0] = v.x; tile[kk][c4 + 1] = v.y;
      tile[kk][c4 + 2] = v.z; tile[kk][c4 + 3] = v.w;
    }
    __syncthreads();
    int k8 = (t & 7) << 3, nn = t >> 3;
#pragma unroll
    for (int p = 0; p < 2; ++p) {
      int n = n0 + nn + p * 32;          // global N index (gate*1024 + h)
      int hh = n & 1023, g = n >> 10;
      int R = ((hh >> 5) << 7) + (((hh >> 4) & 1) << 6) + (g << 4) + (hh & 15);
      int nl = nn + p * 32;
      uint4 o;
      o.x = f2bf(tile[k8 + 0][nl]) | ((unsigned)f2bf(tile[k8 + 1][nl]) << 16);
      o.y = f2bf(tile[k8 + 2][nl]) | ((unsigned)f2bf(tile[k8 + 3][nl]) << 16);
      o.z = f2bf(tile[k8 + 4][nl]) | ((unsigned)f2bf(tile[k8 + 5][nl]) << 16);
      o.w = f2bf(tile[k8 + 6][nl]) | ((unsigned)f2bf(tile[k8 + 7][nl]) << 16);
      *(uint4*)(Wt + (size_t)R * 2048 + k0 + k8) = o;
    }
  }
}

// ---------------------------------------------------------------------------
// gemm_lstm R13: R7 structure, MFMA shape 16x16x32 -> 32x32x16.
//   Serial model (validated: 96K LDS + 79K MFMA + bar = 182K cyc = 75.9 us):
//   32x32x16 runs at 4061 FLOP/cyc/CU vs 3378 (ubench 2382-2495 vs 2075 TF)
//   -> MFMA term 79K -> 66K cyc, predicted ~70.6 us. LDS traffic, swizzle,
//   staging, pack, grid, launch_bounds(256,4): all unchanged.
//   Frags: wave-tile 64x64 = 2m x 2n frags of 32x32, 4 k-steps of 16.
//   A/B lane layout: row/col = lane&31, k-chunk = lane>>5 (16B contiguous).
//   C/D: col = lane&31, row = (reg&3)+8*(reg>>2)+4*(lane>>5)  [m74/m101].
//   Gate decode: B-frag j covers Wt rows wn*64+j*32..+32 -> gate =
//   (j<<1)|(c>>4), h = h0+(wn<<4)+(c&15), c = lane&31. Lane holds gates
//   {0,2} (c<16) or {1,3} (c>=16) for the SAME h as partner lane l^16:
//   one shfl_xor(16) pair per (i, reg-half); c<16 stores regs 0-7,
//   c>=16 stores regs 8-15 (disjoint rows, each output written once).
// ---------------------------------------------------------------------------
__device__ inline void gl_lds16(const void* g, void* l) {
  __builtin_amdgcn_global_load_lds(
      (const __attribute__((address_space(1))) void*)g,
      (__attribute__((address_space(3))) void*)l, 16, 0, 0);
}

__device__ inline float sigm(float x)  { return 1.0f / (1.0f + __expf(-x)); }
__device__ inline float tanhx(float x) { return 2.0f / (1.0f + __expf(-2.0f * x)) - 1.0f; }

__global__ void __launch_bounds__(256, 4) gemm_lstm(
    const unsigned short* __restrict__ A,
    const unsigned short* __restrict__ Bt,
    const float* __restrict__ ct,
    const float* __restrict__ bi,
    const float* __restrict__ bh,
    float* __restrict__ out) {
  constexpr int K = 2048;
  __shared__ char AsB[128 * 128];  // 128 rows x 64 bf16 (128 B)
  __shared__ char BsB[128 * 128];
  const int tid  = threadIdx.x;
  const int lane = tid & 63;
  const int wave = tid >> 6;
  const int wm = wave >> 1, wn = wave & 1;

  // ---- XCD supertile swizzle (bijection on [0,1024)) ----
  const int bid = blockIdx.x;
  const int g  = bid & 7;
  const int s  = bid >> 3;
  const int bx = (g << 2) + (s & 3);
  const int by = ((s >> 4) << 2) + ((s >> 2) & 3);
  const int m0 = by << 7;
  const int n0 = bx << 7;   // linear row block in permuted W
  const int h0 = bx << 5;   // 32 h per block

  // epilogue lane mapping + bias preload
  const int c32  = lane & 31;           // C/D column
  const int kq2  = lane >> 5;           // k-chunk / C-row-offset select
  const int h    = h0 + (wn << 4) + (c32 & 15);
  float bias[4];
#pragma unroll
  for (int j = 0; j < 4; ++j) bias[j] = bi[j * 1024 + h] + bh[j * 1024 + h];

  // ---- staging: uniform base (SGPR) + ONE shared per-lane offset ----
  const int sr = tid >> 3;                              // LDS row 0..31 (+p*32)
  const int cs = ((tid & 7) ^ (sr & 7)) << 4;           // XOR-swizzled source chunk
  const unsigned voff = (unsigned)sr * 4096u + (unsigned)cs;
  const char* aBase = (const char*)A  + (size_t)m0 * 4096;
  const char* bBase = (const char*)Bt + (size_t)n0 * 4096;
  char* aD = AsB + tid * 16;
  char* bD = BsB + tid * 16;

  floatx16 acc[2][2] = {};
  // LDS fragment bases (row = 128 B; chunk phys = logical ^ (row&7), row&7 = lane&7)
  const int keyc = lane & 7;
  const char* aR0 = AsB + ((wm << 6) + c32) * 128;   // i=0 base; i=1: +4096
  const char* bR0 = BsB + ((wn << 6) + c32) * 128;   // j=0 base; j=1: +4096

  for (int ks = 0; ks < K; ks += 64) {
    const char* aIt = aBase + ks * 2;   // uniform
    const char* bIt = bBase + ks * 2;   // uniform
#pragma unroll
    for (int p = 0; p < 4; ++p) gl_lds16(aIt + p * 131072 + voff, aD + p * 4096);
#pragma unroll
    for (int p = 0; p < 4; ++p) gl_lds16(bIt + p * 131072 + voff, bD + p * 4096);
    __syncthreads();
#pragma unroll
    for (int st = 0; st < 4; ++st) {
      const int ofs = (((st << 1) + kq2) ^ keyc) << 4;   // 16B chunk in 64-k row
      short8 a0 = *(const short8*)(aR0 + ofs);
      short8 a1 = *(const short8*)(aR0 + 4096 + ofs);
      short8 b0 = *(const short8*)(bR0 + ofs);
      short8 b1 = *(const short8*)(bR0 + 4096 + ofs);
      acc[0][0] = __builtin_amdgcn_mfma_f32_32x32x16_bf16(a0, b0, acc[0][0], 0, 0, 0);
      acc[0][1] = __builtin_amdgcn_mfma_f32_32x32x16_bf16(a0, b1, acc[0][1], 0, 0, 0);
      acc[1][0] = __builtin_amdgcn_mfma_f32_32x32x16_bf16(a1, b0, acc[1][0], 0, 0, 0);
      acc[1][1] = __builtin_amdgcn_mfma_f32_32x32x16_bf16(a1, b1, acc[1][1], 0, 0, 0);
    }
    __syncthreads();
  }

  // ---- fused LSTM epilogue (32x32 C/D layout + partner-lane gate swap) ----
  const bool lo = (c32 < 16);
  float cv[2][8];
#pragma unroll
  for (int i2 = 0; i2 < 2; ++i2)
#pragma unroll
    for (int r = 0; r < 8; ++r) {
      int rr = lo ? r : r + 8;
      int rloc = (rr & 3) + ((rr >> 2) << 3) + (kq2 << 2);
      int row = m0 + (wm << 6) + i2 * 32 + rloc;
      cv[i2][r] = ct[(size_t)row * 1024 + h];
    }
#pragma unroll
  for (int i2 = 0; i2 < 2; ++i2) {
#pragma unroll
    for (int r = 0; r < 8; ++r) {
      // send the half the partner needs; receive the half we need
      float s0 = lo ? acc[i2][0][r + 8] : acc[i2][0][r];
      float s1 = lo ? acc[i2][1][r + 8] : acc[i2][1][r];
      float e0 = __shfl_xor(s0, 16);
      float e1 = __shfl_xor(s1, 16);
      float a0 = lo ? acc[i2][0][r] : acc[i2][0][r + 8];
      float a1 = lo ? acc[i2][1][r] : acc[i2][1][r + 8];
      // lane c<16 holds gates {0,2}; partner holds {1,3} for the same h
      float ig = lo ? a0 : e0;
      float fg = lo ? e0 : a0;
      float gg = lo ? a1 : e1;
      float og = lo ? e1 : a1;
      int rr = lo ? r : r + 8;
      int rloc = (rr & 3) + ((rr >> 2) << 3) + (kq2 << 2);
      int row = m0 + (wm << 6) + i2 * 32 + rloc;
      size_t o = (size_t)row * 1024 + h;
      float iv = sigm(ig + bias[0]);
      float fv = sigm(fg + bias[1]);
      float gv = tanhx(gg + bias[2]);
      float ov = sigm(og + bias[3]);
      float cn = fv * cv[i2][r] + iv * gv;
      out[o] = ov * tanhx(cn);
      out[4194304 + o] = cn;
    }
  }
}

// ---------------------------------------------------------------------------
extern "C" void kernel_launch(void* const* d_in, const int* in_sizes, int n_in,
                              void* d_out, int out_size, void* d_ws, size_t ws_size,
                              hipStream_t stream) {
  const float* x  = (const float*)d_in[0];
  const float* ht = (const float*)d_in[1];
  const float* ct = (const float*)d_in[2];
  const float* wi = (const float*)d_in[3];
  const float* wh = (const float*)d_in[4];
  const float* bi = (const float*)d_in[5];
  const float* bh = (const float*)d_in[6];
  float* out = (float*)d_out;

  char* ws = (char*)d_ws;
  unsigned short* Abf = (unsigned short*)ws;                 // 16 MiB
  unsigned short* Wbf = (unsigned short*)(ws + (16u << 20)); // 16 MiB

  pack_all<<<6144, 256, 0, stream>>>(x, ht, wi, wh, Abf, Wbf);
  gemm_lstm<<<1024, 256, 0, stream>>>(Abf, Wbf, ct, bi, bh, out);
}